// Round 5
// baseline (115.818 us; speedup 1.0000x reference)
//
#include <hip/hip_runtime.h>
#include <math.h>

#define BB 4
#define CC 128
#define HW 4096
// sqrt(10 * log2(e)) — folds 1/tau AND exp->exp2 into both normalized sides:
// sim' = sim * log2(e), so exp(sim) == exp2(sim').
#define SCF 3.798282565f

typedef short short8 __attribute__((ext_vector_type(8)));
typedef float f32x4 __attribute__((ext_vector_type(4)));

static __device__ inline unsigned short f2bf(float f) {
  // round-to-nearest-even fp32 -> bf16 (inputs are finite)
  unsigned int u = __float_as_uint(f);
  u += 0x7fffu + ((u >> 16) & 1u);
  return (unsigned short)(u >> 16);
}

// K1: per 32-position tile: inv-norms of A and B, fp32 diagonal similarity,
// zero expsum + completion counter, and write bf16 normalized*SCF features
// transposed to [b][pos][c] with XOR-swizzled 16B chunks (position q holds
// data chunk q^(n&7)) so k_main's global_load_lds staging is an identity copy
// while MFMA fragment ds_reads stay low-conflict.
__global__ __launch_bounds__(256) void k_prep(const float* __restrict__ fA,
                                              const float* __restrict__ fB,
                                              unsigned short* __restrict__ fAn,
                                              unsigned short* __restrict__ fBn,
                                              float* __restrict__ diag,
                                              float* __restrict__ expsum,
                                              float* __restrict__ acc) {
  __shared__ float sA[32 * 129];
  __shared__ float sB[32 * 129];
  __shared__ float red[3 * 256];

  const int bid = blockIdx.x;          // 0..511 : b*128 + tile
  const int b   = bid >> 7;
  const int n0  = (bid & 127) * 32;
  const int tid = threadIdx.x;
  const int cR  = tid >> 5;            // 0..7
  const int n   = tid & 31;            // 0..31

  if (bid == 0 && tid == 0) { acc[0] = 0.f; acc[1] = 0.f; ((unsigned*)acc)[2] = 0u; }

  const float* pa = fA + (size_t)b * CC * HW + n0 + n;
  const float* pb = fB + (size_t)b * CC * HW + n0 + n;

  float ssa = 0.f, ssb = 0.f, dot = 0.f;
  #pragma unroll
  for (int it = 0; it < 16; ++it) {
    int c = it * 8 + cR;
    float va = pa[(size_t)c * HW];
    float vb = pb[(size_t)c * HW];
    sA[n * 129 + c] = va;
    sB[n * 129 + c] = vb;
    ssa = fmaf(va, va, ssa);
    ssb = fmaf(vb, vb, ssb);
    dot = fmaf(va, vb, dot);
  }
  red[tid] = ssa; red[256 + tid] = ssb; red[512 + tid] = dot;
  __syncthreads();

  if (tid < 32) {
    float sa = 0.f, sb = 0.f, dt = 0.f;
    #pragma unroll
    for (int k = 0; k < 8; ++k) {
      sa += red[k * 32 + tid];
      sb += red[256 + k * 32 + tid];
      dt += red[512 + k * 32 + tid];
    }
    float ia = 1.f / fmaxf(sqrtf(sa), 1e-12f);
    float ib = 1.f / fmaxf(sqrtf(sb), 1e-12f);
    int gidx = b * HW + n0 + tid;
    diag[gidx]   = dt * ia * ib * 10.f;   // true sim scale (1/tau)
    expsum[gidx] = 0.f;
    red[tid]      = ia * SCF;   // sole reader/writer of these slots
    red[32 + tid] = ib * SCF;
  }
  __syncthreads();

  #pragma unroll
  for (int r = 0; r < 2; ++r) {
    int L  = r * 256 + tid;
    int nn = L >> 4;                  // 0..31
    int q  = L & 15;                  // store position within row
    int c0 = (q ^ (nn & 7)) * 8;      // data chunk (swizzle)
    size_t base = ((size_t)b * HW + n0 + nn) * 128 + q * 8;
    {
      float sc = red[nn];
      const float* s = &sA[nn * 129 + c0];
      uint4 v;
      v.x = f2bf(s[0]*sc) | ((unsigned)f2bf(s[1]*sc) << 16);
      v.y = f2bf(s[2]*sc) | ((unsigned)f2bf(s[3]*sc) << 16);
      v.z = f2bf(s[4]*sc) | ((unsigned)f2bf(s[5]*sc) << 16);
      v.w = f2bf(s[6]*sc) | ((unsigned)f2bf(s[7]*sc) << 16);
      *(uint4*)(fAn + base) = v;
    }
    {
      float sc = red[32 + nn];
      const float* s = &sB[nn * 129 + c0];
      uint4 v;
      v.x = f2bf(s[0]*sc) | ((unsigned)f2bf(s[1]*sc) << 16);
      v.y = f2bf(s[2]*sc) | ((unsigned)f2bf(s[3]*sc) << 16);
      v.z = f2bf(s[4]*sc) | ((unsigned)f2bf(s[5]*sc) << 16);
      v.w = f2bf(s[6]*sc) | ((unsigned)f2bf(s[7]*sc) << 16);
      *(uint4*)(fBn + base) = v;
    }
  }
}

// K2: B-tile in registers (read once from LDS, 64 VGPR), A swept in 64-row
// chunks through a 16KB ping-pong pair with one barrier per iteration: the
// global_load_lds prefetch of A(it+1) is issued before compute(it), so the
// vmcnt drain at the end-of-iter barrier lands after a full compute phase.
// Fused exp2 column-sum epilogue + last-block loss finish.
// Registers/wave ~= 64 (bf) + 32 acc + ~30 misc -> 2 waves/SIMD; LDS = 64 KB
// exactly -> 2 blocks/CU.
__global__ __launch_bounds__(256, 2) void k_main(const unsigned short* __restrict__ fAn,
                                                 const unsigned short* __restrict__ fBn,
                                                 float* __restrict__ expsum,
                                                 const float* __restrict__ diag,
                                                 const float* __restrict__ mask,
                                                 float* __restrict__ acc,
                                                 float* __restrict__ out) {
  __shared__ unsigned short sB[16384];      // 32 KB B tile (128 cols x 128 ch)
  __shared__ unsigned short sA[2][8192];    // 2 x 16 KB A chunks (64 rows)

  const int bid = blockIdx.x;                // 0..511
  const int x   = bid & 7;                   // XCD
  const int t   = bid >> 3;                  // 0..63
  const int b   = x & 3;
  const int nq  = (x >> 2) | ((t & 1) << 1); // 0..3
  const int mt  = t >> 1;                    // 0..31
  const int m0  = mt * 128;
  const int nbase = nq * 1024;
  const int tid = threadIdx.x;

  const int wv   = tid >> 6;
  const int lane = tid & 63;
  const int ml   = lane & 15;
  const int g    = lane >> 4;
  const int wn   = (wv & 1) * 32;    // wave n-offset within 64-row A chunk
  const int wm   = (wv >> 1) * 64;   // wave m-offset within B tile

  const unsigned short* gAbase = fAn + ((size_t)b * HW + nbase) * 128;

  // initial staging: B tile (2048 chunks) + A chunk 0 (1024 chunks)
  {
    const unsigned short* gB = fBn + ((size_t)b * HW + m0) * 128;
    #pragma unroll
    for (int r = 0; r < 8; ++r) {
      int L = r * 256 + tid;
      __builtin_amdgcn_global_load_lds(
          (const __attribute__((address_space(1))) unsigned int*)(gB + (size_t)L * 8),
          (__attribute__((address_space(3))) unsigned int*)(sB + L * 8), 16, 0, 0);
    }
    #pragma unroll
    for (int r = 0; r < 4; ++r) {
      int L = r * 256 + tid;
      __builtin_amdgcn_global_load_lds(
          (const __attribute__((address_space(1))) unsigned int*)(gAbase + (size_t)L * 8),
          (__attribute__((address_space(3))) unsigned int*)(sA[0] + L * 8), 16, 0, 0);
    }
  }
  __syncthreads();

  // extract B fragments to registers (sB is never written again)
  short8 bf[4][4];
  #pragma unroll
  for (int kc = 0; kc < 4; ++kc) {
    int q = kc * 4 + g;
    #pragma unroll
    for (int j = 0; j < 4; ++j) {
      int nb = wm + j * 16 + ml;
      bf[kc][j] = *(const short8*)(sB + nb * 128 + ((q ^ (nb & 7)) * 8));
    }
  }

  float colAcc[4] = {0.f, 0.f, 0.f, 0.f};

  for (int it = 0; it < 16; ++it) {
    // prefetch A(it+1) into the pong buffer (overlaps this iter's compute)
    if (it < 15) {
      const unsigned short* gA = gAbase + (size_t)(it + 1) * 8192;
      unsigned short* dst = sA[(it + 1) & 1];
      #pragma unroll
      for (int r = 0; r < 4; ++r) {
        int L = r * 256 + tid;
        __builtin_amdgcn_global_load_lds(
            (const __attribute__((address_space(1))) unsigned int*)(gA + (size_t)L * 8),
            (__attribute__((address_space(3))) unsigned int*)(dst + L * 8), 16, 0, 0);
      }
    }

    // compute on the ping buffer: A-frag ds_reads interleave with MFMA
    const unsigned short* bufc = sA[it & 1];
    f32x4 acc4[2][4] = {};
    #pragma unroll
    for (int kc = 0; kc < 4; ++kc) {
      int q = kc * 4 + g;
      short8 af0, af1;
      {
        int na = wn + ml;
        af0 = *(const short8*)(bufc + na * 128 + ((q ^ (na & 7)) * 8));
        na = wn + 16 + ml;
        af1 = *(const short8*)(bufc + na * 128 + ((q ^ (na & 7)) * 8));
      }
      #pragma unroll
      for (int j = 0; j < 4; ++j) {
        acc4[0][j] = __builtin_amdgcn_mfma_f32_16x16x32_bf16(af0, bf[kc][j], acc4[0][j], 0, 0, 0);
        acc4[1][j] = __builtin_amdgcn_mfma_f32_16x16x32_bf16(af1, bf[kc][j], acc4[1][j], 0, 0, 0);
      }
    }
    // epilogue: per-column sums of exp2(sim'). C layout: col=lane&15, row=g*4+r.
    // |sim'| <= 14.43 -> exp2 within fp32 range, no shift needed.
    #pragma unroll
    for (int j = 0; j < 4; ++j) {
      float e = 0.f;
      #pragma unroll
      for (int i = 0; i < 2; ++i)
        #pragma unroll
        for (int r = 0; r < 4; ++r)
          e += exp2f(acc4[i][j][r]);
      colAcc[j] += e;
    }

    __syncthreads();   // (a) all waves done reading ping; (b) drains prefetch
  }

  // per-column reduce across row-groups, one atomic per column per wave
  #pragma unroll
  for (int j = 0; j < 4; ++j) {
    float e = colAcc[j];
    e += __shfl_xor(e, 16, 64);
    e += __shfl_xor(e, 32, 64);
    if (lane < 16)
      atomicAdd(&expsum[(size_t)b * HW + m0 + wm + j * 16 + lane], e);
  }

  // last-block loss finish (flag via LDS reuse; keeps LDS at exactly 64 KB)
  unsigned* flag = (unsigned*)sA;
  __syncthreads();                 // atomics issued by all waves
  if (tid == 0) {
    __threadfence();
    flag[0] = (atomicAdd((unsigned*)(acc + 2), 1u) == 511u) ? 1u : 0u;
  }
  __syncthreads();
  if (flag[0]) {
    float num = 0.f, den = 0.f;
    #pragma unroll 4
    for (int i = tid; i < BB * HW; i += 256) {
      float es = __hip_atomic_load(expsum + i, __ATOMIC_RELAXED, __HIP_MEMORY_SCOPE_AGENT);
      float mv = mask[i];
      num = fmaf(mv, __logf(es) - diag[i], num);   // ln(sum exp(sim)) - sim_kk
      den += mv;
    }
    #pragma unroll
    for (int off = 32; off; off >>= 1) {
      num += __shfl_down(num, off, 64);
      den += __shfl_down(den, off, 64);
    }
    float* red = (float*)sB;
    if (lane == 0) { red[wv] = num; red[8 + wv] = den; }
    __syncthreads();
    if (tid == 0) {
      float n = red[0] + red[1] + red[2] + red[3];
      float d = red[8] + red[9] + red[10] + red[11];
      out[0] = n / (d + 1e-6f);
    }
  }
}

extern "C" void kernel_launch(void* const* d_in, const int* in_sizes, int n_in,
                              void* d_out, int out_size, void* d_ws, size_t ws_size,
                              hipStream_t stream) {
  const float* feat_A = (const float*)d_in[0];
  const float* feat_B = (const float*)d_in[1];
  // d_in[2] = H_mat : unused by the reference computation
  const float* vmask  = (const float*)d_in[3];

  unsigned short* fAn = (unsigned short*)d_ws;            // 4 MB bf16 [b][n][c] swizzled
  unsigned short* fBn = fAn + (size_t)BB * HW * CC;       // 4 MB
  float* diag   = (float*)(fBn + (size_t)BB * HW * CC);   // 64 KB
  float* expsum = diag + BB * HW;                         // 64 KB
  float* acc    = expsum + BB * HW;                       // num, den, counter
  float* out    = (float*)d_out;

  k_prep<<<512, 256, 0, stream>>>(feat_A, feat_B, fAn, fBn, diag, expsum, acc);
  k_main<<<512, 256, 0, stream>>>(fAn, fBn, expsum, diag, vmask, acc, out);
}